// Round 12
// baseline (450.244 us; speedup 1.0000x reference)
//
#include <hip/hip_runtime.h>
#include <hip/hip_bf16.h>
#include <stdint.h>

#define DIMM 1024
#define HEADS 16
#define HD 64
#define BB 2
#define SS 2048
#define NTOK (BB*SS)

typedef __attribute__((ext_vector_type(8))) __bf16 bf16x8;
typedef __attribute__((ext_vector_type(4))) __bf16 bf16x4;
typedef __attribute__((ext_vector_type(4))) float f32x4;

__device__ __forceinline__ f32x4 mfma16(bf16x8 a, bf16x8 b, f32x4 c) {
  return __builtin_amdgcn_mfma_f32_16x16x32_bf16(a, b, c, 0, 0, 0);
}

__device__ __forceinline__ void gload_lds16(const void* g, void* l) {
  __builtin_amdgcn_global_load_lds(
      (__attribute__((address_space(1))) void*)(void*)g,
      (__attribute__((address_space(3))) void*)l,
      16, 0, 0);
}

#define LOG2E 1.4426950408889634f
#define C2 (0.125f * LOG2E)      /* score scale folded into log2 domain */
#define NBRAW (-8e9f)            /* raw-domain masked score: -8e9*0.125 = -1e9 */

// ---------------- convert fp32 -> bf16 ----------------
struct CvtArgs {
  const float* src[7];
  __bf16* dst[7];
  int n[7];
};

__global__ __launch_bounds__(256) void cvt_kernel(CvtArgs a) {
  const int t = blockIdx.y;
  const long i = ((long)blockIdx.x * 256 + threadIdx.x) * 8;
  if (i >= a.n[t]) return;
  const float* s = a.src[t] + i;
  f32x4 x0 = *(const f32x4*)s;
  f32x4 x1 = *(const f32x4*)(s + 4);
  bf16x8 o;
  o[0] = (__bf16)x0[0]; o[1] = (__bf16)x0[1]; o[2] = (__bf16)x0[2]; o[3] = (__bf16)x0[3];
  o[4] = (__bf16)x1[0]; o[5] = (__bf16)x1[1]; o[6] = (__bf16)x1[2]; o[7] = (__bf16)x1[3];
  *(bf16x8*)(a.dst[t] + i) = o;
}

// ---------------- mask -> bitmask (128 words: [b][k>>5]) ----------------
__global__ void maskbits_kernel(const int* __restrict__ msk, uint32_t* __restrict__ mbits) {
  int j = threadIdx.x;
  if (j >= 128) return;
  const int* src = msk + j * 32;
  uint32_t wdd = 0;
#pragma unroll
  for (int i = 0; i < 32; ++i) wdd |= (src[i] != 0 ? 1u : 0u) << i;
  mbits[j] = wdd;
}

// ---------------- GEMM: C[m,n] = sum_k A[m,k]*B[n,k] + bias[n] ----------------
struct GemmArgs {
  const __bf16* A[3];
  const __bf16* B[3];
  const float* bias[3];
  void* out[3];
  int mode[3];
};

__global__ __launch_bounds__(256) void gemm_bt(GemmArgs ga) {
  const int z = blockIdx.z;
  const __bf16* __restrict__ A  = ga.A[z];
  const __bf16* __restrict__ Bm = ga.B[z];
  const float* __restrict__ bias = ga.bias[z];
  void* Cout = ga.out[z];
  const int mode = ga.mode[z];

  __shared__ __align__(16) char sA[2][16384];
  __shared__ __align__(16) char sB[2][16384];
  const int tid = threadIdx.x;
  const int w = tid >> 6, l = tid & 63;
  const int wr = w >> 1, wc = w & 1;
  const int lg = l >> 4, lr = l & 15;
  const int m0 = blockIdx.y * 128, n0 = blockIdx.x * 128;

  f32x4 acc[4][4] = {};

  auto stage = [&](int k0, int buf) {
#pragma unroll
    for (int i = 0; i < 4; ++i) {
      int c = (i * 4 + w) * 64 + l;
      int row = c >> 3, ch = c & 7;
      gload_lds16(A + (size_t)(m0 + row) * 1024 + k0 + ((ch ^ (row & 7)) << 3),
                  &sA[buf][(i * 4 + w) * 1024]);
    }
#pragma unroll
    for (int i = 0; i < 4; ++i) {
      int c = (i * 4 + w) * 64 + l;
      int row = c >> 3, ch = c & 7;
      gload_lds16(Bm + (size_t)(n0 + row) * 1024 + k0 + ((ch ^ (row & 7)) << 3),
                  &sB[buf][(i * 4 + w) * 1024]);
    }
  };

  stage(0, 0);
  __syncthreads();

  for (int ks = 0; ks < 16; ++ks) {
    const int cur = ks & 1;
    if (ks < 15) stage((ks + 1) * 64, cur ^ 1);
#pragma unroll
    for (int kk = 0; kk < 2; ++kk) {
      bf16x8 af[4], bfv[4];
#pragma unroll
      for (int fm = 0; fm < 4; ++fm) {
        int row = wr * 64 + fm * 16 + lr;
        af[fm] = *(const bf16x8*)&sA[cur][row * 128 + (((kk * 4 + lg) ^ (row & 7)) << 4)];
      }
#pragma unroll
      for (int fn = 0; fn < 4; ++fn) {
        int row = wc * 64 + fn * 16 + lr;
        bfv[fn] = *(const bf16x8*)&sB[cur][row * 128 + (((kk * 4 + lg) ^ (row & 7)) << 4)];
      }
#pragma unroll
      for (int fm = 0; fm < 4; ++fm)
#pragma unroll
        for (int fn = 0; fn < 4; ++fn)
          acc[fm][fn] = mfma16(af[fm], bfv[fn], acc[fm][fn]);
    }
    __syncthreads();
  }

#pragma unroll
  for (int fm = 0; fm < 4; ++fm) {
#pragma unroll
    for (int fn = 0; fn < 4; ++fn) {
      const int n = n0 + wc * 64 + fn * 16 + lr;
      const int mb = m0 + wr * 64 + fm * 16 + 4 * lg;
      const float bval = bias[n];
      f32x4 vv = acc[fm][fn];
      if (mode == 2) {
        float* C = (float*)Cout;
#pragma unroll
        for (int r = 0; r < 4; ++r)
          C[(size_t)(mb + r) * 1024 + n] = vv[r] + bval;
      } else if (mode == 0) {
        __bf16* C = (__bf16*)Cout;
        const int hh = n >> 6, d = n & 63;
#pragma unroll
        for (int r = 0; r < 4; ++r) {
          int m = mb + r;
          C[(((size_t)(m >> 11) * 16 + hh) * 2048 + (m & 2047)) * 64 + d] =
              (__bf16)(vv[r] + bval);
        }
      } else {
        __bf16* C = (__bf16*)Cout;
        const int hh = n >> 6, d = n & 63;
        bf16x4 pk;
#pragma unroll
        for (int r = 0; r < 4; ++r) pk[r] = (__bf16)(vv[r] + bval);
        *(bf16x4*)(C + (((size_t)(mb >> 11) * 16 + hh) * 64 + d) * 2048 + (mb & 2047)) = pk;
      }
    }
  }
}

// ---------------- fused attention ----------------
// BARRIER-FREE: K/V read directly from global (L2-resident via XCD pinning;
// guide CM#7 - don't LDS-stage what L2-fits). No staging -> no __syncthreads
// in the k-loop -> waves decouple; store drain of one wave overlaps compute
// of others. LDS = sPF only (16 KB, wave-private transpose buffer) ->
// 256B-run NT stores. grid 1024 x 4 waves.
__global__ __launch_bounds__(256) void attn_kernel(
    const __bf16* __restrict__ Qh, const __bf16* __restrict__ Kh,
    const __bf16* __restrict__ Vt, const uint32_t* __restrict__ mbits,
    float* __restrict__ attnW, __bf16* __restrict__ ctx)
{
  __shared__ __align__(16) float sPF[4][16][64];   // wave-private P full tile

  const int tid = threadIdx.x;
  const int w = tid >> 6, l = tid & 63;
  const int lg = l >> 4, lr = l & 15;

  const int bid = blockIdx.x;
  const int xcd = bid & 7, j = bid >> 3;
  const int bh = xcd * 4 + (j >> 5);      // each head pinned to one XCD
  const int q0 = (j & 31) * 64;
  const int b = bh >> 4, h = bh & 15;

  const __bf16* qbase = Qh + ((size_t)bh * SS + q0 + w * 16 + lr) * HD;
  bf16x8 qf0 = *(const bf16x8*)(qbase + lg * 8);
  bf16x8 qf1 = *(const bf16x8*)(qbase + 32 + lg * 8);

  const __bf16* Khead = Kh + (size_t)bh * SS * HD;
  const __bf16* Vhead = Vt + (size_t)bh * HD * SS;
  const uint32_t* mrow = mbits + b * 64;

  // ---- pass 1: per-row sumexp (max-free, clamped). lane q = lr, k = 4lg+r ----
  float lsum = 0.0f;

  for (int t = 0; t < 32; ++t) {
    const int k0 = t * 64;
    const uint32_t mw0 = mrow[2 * t], mw1 = mrow[2 * t + 1];
    const bool fast = ((mw0 & mw1) == 0xFFFFFFFFu);

#pragma unroll
    for (int sub = 0; sub < 4; ++sub) {
      const __bf16* kp = Khead + (size_t)(k0 + sub * 16 + lr) * HD + lg * 8;
      bf16x8 k0f = *(const bf16x8*)kp;          // k-dim elems lg*8..+8
      bf16x8 k1f = *(const bf16x8*)(kp + 32);   // k-dim elems 32+lg*8..+8
      __builtin_amdgcn_s_setprio(1);
      f32x4 a = {};
      a = mfma16(k0f, qf0, a);
      a = mfma16(k1f, qf1, a);
      __builtin_amdgcn_s_setprio(0);
      if (!fast) {
        uint32_t bits = ((sub < 2) ? mw0 : mw1) >> ((sub & 1) * 16 + 4 * lg);
#pragma unroll
        for (int r = 0; r < 4; ++r) a[r] = ((bits >> r) & 1) ? a[r] : NBRAW;
      }
#pragma unroll
      for (int r = 0; r < 4; ++r)
        lsum += __builtin_amdgcn_exp2f(fminf(a[r] * C2, 80.0f));
    }
  }

  lsum += __shfl_xor(lsum, 16);
  lsum += __shfl_xor(lsum, 32);
  const float rl = 1.0f / lsum;

  f32x4 Oa[4] = {};
  float* pwbase = attnW + ((size_t)bh * SS + q0 + w * 16) * SS;

  // ---- pass 2: QK -> P(sPF) -> 256B-run NT store -> PV. No barriers. ----
  for (int t = 0; t < 32; ++t) {
    const int k0 = t * 64;
    const uint32_t mw0 = mrow[2 * t], mw1 = mrow[2 * t + 1];
    const bool fast = ((mw0 & mw1) == 0xFFFFFFFFu);

    // -- compute all 4 sub-tiles (64 k-cols), write f32 P into sPF (swizzled) --
#pragma unroll
    for (int sub = 0; sub < 4; ++sub) {
      const __bf16* kp = Khead + (size_t)(k0 + sub * 16 + lr) * HD + lg * 8;
      bf16x8 k0f = *(const bf16x8*)kp;
      bf16x8 k1f = *(const bf16x8*)(kp + 32);
      __builtin_amdgcn_s_setprio(1);
      f32x4 a = {};
      a = mfma16(k0f, qf0, a);
      a = mfma16(k1f, qf1, a);
      __builtin_amdgcn_s_setprio(0);
      if (!fast) {
        uint32_t bits = ((sub < 2) ? mw0 : mw1) >> ((sub & 1) * 16 + 4 * lg);
#pragma unroll
        for (int r = 0; r < 4; ++r) a[r] = ((bits >> r) & 1) ? a[r] : NBRAW;
      }
      f32x4 p;
#pragma unroll
      for (int r = 0; r < 4; ++r)
        p[r] = __builtin_amdgcn_exp2f(fminf(a[r] * C2, 80.0f)) * rl;
      const int cp = (sub * 4 + lg) ^ (lr & 7);      // 16B chunk, swizzled
      *(f32x4*)&sPF[w][lr][cp * 4] = p;
    }

    // -- transposed NT store: 4 instrs x (4 rows x 256B contiguous) --
    // (same-wave LDS: ds ops are wave-ordered; sPF is wave-private -> no sync)
#pragma unroll
    for (int i = 0; i < 4; ++i) {
      const int row = i * 4 + lg;
      const int cp = lr ^ (row & 7);
      f32x4 pv4 = *(const f32x4*)&sPF[w][row][cp * 4];
      __builtin_nontemporal_store(pv4,
          (f32x4*)(pwbase + (size_t)row * SS + k0 + lr * 4));
    }

    // -- PV: A-operand from sPF (f32 -> bf16), B = V^T rows direct from L2 --
#pragma unroll
    for (int hh = 0; hh < 2; ++hh) {
      f32x4 pa_lo = *(const f32x4*)&sPF[w][lr][(((hh * 8 + 2 * lg) ^ (lr & 7)) * 4)];
      f32x4 pa_hi = *(const f32x4*)&sPF[w][lr][(((hh * 8 + 2 * lg + 1) ^ (lr & 7)) * 4)];
      bf16x8 pa;
#pragma unroll
      for (int r = 0; r < 4; ++r) {
        pa[r] = (__bf16)pa_lo[r];
        pa[4 + r] = (__bf16)pa_hi[r];
      }
      __builtin_amdgcn_s_setprio(1);
#pragma unroll
      for (int dg = 0; dg < 4; ++dg) {
        const int d = dg * 16 + lr;
        bf16x8 vb = *(const bf16x8*)(Vhead + (size_t)d * SS + k0 + (hh * 4 + lg) * 8);
        Oa[dg] = mfma16(pa, vb, Oa[dg]);
      }
      __builtin_amdgcn_s_setprio(0);
    }
  }

  // epilogue: context -> [b*s][h*64+d] bf16 (Oa: q = 4lg+r, d = dg*16+lr)
#pragma unroll
  for (int dg = 0; dg < 4; ++dg)
#pragma unroll
    for (int r = 0; r < 4; ++r)
      ctx[(size_t)(b * SS + q0 + w * 16 + 4 * lg + r) * DIMM + h * HD + dg * 16 + lr] =
          (__bf16)Oa[dg][r];
}

// ---------------- launch ----------------
extern "C" void kernel_launch(void* const* d_in, const int* in_sizes, int n_in,
                              void* d_out, int out_size, void* d_ws, size_t ws_size,
                              hipStream_t stream)
{
  const float* q   = (const float*)d_in[0];
  const float* k   = (const float*)d_in[1];
  const float* v   = (const float*)d_in[2];
  const int*   msk = (const int*)d_in[3];
  const float* Wq  = (const float*)d_in[4];
  const float* bq  = (const float*)d_in[5];
  const float* Wk  = (const float*)d_in[6];
  const float* bk  = (const float*)d_in[7];
  const float* Wv  = (const float*)d_in[8];
  const float* bv  = (const float*)d_in[9];
  const float* Wo  = (const float*)d_in[10];
  const float* bo  = (const float*)d_in[11];

  char* ws = (char*)d_ws;
  __bf16* xq  = (__bf16*)(ws);
  __bf16* xk  = (__bf16*)(ws + (8u << 20));
  __bf16* xv  = (__bf16*)(ws + (16u << 20));
  __bf16* wqb = (__bf16*)(ws + (24u << 20));
  __bf16* wkb = (__bf16*)(ws + (26u << 20));
  __bf16* wvb = (__bf16*)(ws + (28u << 20));
  __bf16* wob = (__bf16*)(ws + (30u << 20));
  __bf16* Qh  = (__bf16*)(ws + (32u << 20));
  __bf16* Kh  = (__bf16*)(ws + (40u << 20));
  __bf16* Vt  = (__bf16*)(ws + (48u << 20));
  __bf16* ctx = (__bf16*)(ws + (56u << 20));
  uint32_t* mbits = (uint32_t*)(ws + (64u << 20));

  CvtArgs ca;
  ca.src[0] = q;  ca.dst[0] = xq;  ca.n[0] = NTOK * DIMM;
  ca.src[1] = k;  ca.dst[1] = xk;  ca.n[1] = NTOK * DIMM;
  ca.src[2] = v;  ca.dst[2] = xv;  ca.n[2] = NTOK * DIMM;
  ca.src[3] = Wq; ca.dst[3] = wqb; ca.n[3] = DIMM * DIMM;
  ca.src[4] = Wk; ca.dst[4] = wkb; ca.n[4] = DIMM * DIMM;
  ca.src[5] = Wv; ca.dst[5] = wvb; ca.n[5] = DIMM * DIMM;
  ca.src[6] = Wo; ca.dst[6] = wob; ca.n[6] = DIMM * DIMM;
  cvt_kernel<<<dim3(2048, 7, 1), 256, 0, stream>>>(ca);
  maskbits_kernel<<<1, 128, 0, stream>>>(msk, mbits);

  GemmArgs g1;
  g1.A[0] = xq; g1.B[0] = wqb; g1.bias[0] = bq; g1.out[0] = (void*)Qh; g1.mode[0] = 0;
  g1.A[1] = xk; g1.B[1] = wkb; g1.bias[1] = bk; g1.out[1] = (void*)Kh; g1.mode[1] = 0;
  g1.A[2] = xv; g1.B[2] = wvb; g1.bias[2] = bv; g1.out[2] = (void*)Vt; g1.mode[2] = 1;
  gemm_bt<<<dim3(8, 32, 3), 256, 0, stream>>>(g1);

  float* out = (float*)d_out;
  float* attnW = out + (size_t)NTOK * DIMM;
  attn_kernel<<<dim3(1024, 1, 1), 256, 0, stream>>>(Qh, Kh, Vt, mbits, attnW, ctx);

  GemmArgs g2;
  g2.A[0] = ctx; g2.B[0] = wob; g2.bias[0] = bo; g2.out[0] = (void*)out; g2.mode[0] = 2;
  g2.A[1] = ctx; g2.B[1] = wob; g2.bias[1] = bo; g2.out[1] = (void*)out; g2.mode[1] = 2;
  g2.A[2] = ctx; g2.B[2] = wob; g2.bias[2] = bo; g2.out[2] = (void*)out; g2.mode[2] = 2;
  gemm_bt<<<dim3(8, 32, 1), 256, 0, stream>>>(g2);
}

// Round 13
// 368.485 us; speedup vs baseline: 1.2219x; 1.2219x over previous
//
#include <hip/hip_runtime.h>
#include <hip/hip_bf16.h>
#include <stdint.h>

#define DIMM 1024
#define HEADS 16
#define HD 64
#define BB 2
#define SS 2048
#define NTOK (BB*SS)

typedef __attribute__((ext_vector_type(8))) __bf16 bf16x8;
typedef __attribute__((ext_vector_type(4))) __bf16 bf16x4;
typedef __attribute__((ext_vector_type(4))) float f32x4;

__device__ __forceinline__ f32x4 mfma16(bf16x8 a, bf16x8 b, f32x4 c) {
  return __builtin_amdgcn_mfma_f32_16x16x32_bf16(a, b, c, 0, 0, 0);
}

__device__ __forceinline__ void gload_lds16(const void* g, void* l) {
  __builtin_amdgcn_global_load_lds(
      (__attribute__((address_space(1))) void*)(void*)g,
      (__attribute__((address_space(3))) void*)l,
      16, 0, 0);
}

#define LOG2E 1.4426950408889634f
#define C2 (0.125f * LOG2E)      /* score scale folded into log2 domain */
#define NBRAW (-8e9f)            /* raw-domain masked score: -8e9*0.125 = -1e9 */

// ---------------- convert fp32 -> bf16 ----------------
struct CvtArgs {
  const float* src[7];
  __bf16* dst[7];
  int n[7];
};

__global__ __launch_bounds__(256) void cvt_kernel(CvtArgs a) {
  const int t = blockIdx.y;
  const long i = ((long)blockIdx.x * 256 + threadIdx.x) * 8;
  if (i >= a.n[t]) return;
  const float* s = a.src[t] + i;
  f32x4 x0 = *(const f32x4*)s;
  f32x4 x1 = *(const f32x4*)(s + 4);
  bf16x8 o;
  o[0] = (__bf16)x0[0]; o[1] = (__bf16)x0[1]; o[2] = (__bf16)x0[2]; o[3] = (__bf16)x0[3];
  o[4] = (__bf16)x1[0]; o[5] = (__bf16)x1[1]; o[6] = (__bf16)x1[2]; o[7] = (__bf16)x1[3];
  *(bf16x8*)(a.dst[t] + i) = o;
}

// ---------------- mask -> bitmask (128 words: [b][k>>5]) ----------------
__global__ void maskbits_kernel(const int* __restrict__ msk, uint32_t* __restrict__ mbits) {
  int j = threadIdx.x;
  if (j >= 128) return;
  const int* src = msk + j * 32;
  uint32_t wdd = 0;
#pragma unroll
  for (int i = 0; i < 32; ++i) wdd |= (src[i] != 0 ? 1u : 0u) << i;
  mbits[j] = wdd;
}

// ---------------- GEMM: C[m,n] = sum_k A[m,k]*B[n,k] + bias[n] ----------------
struct GemmArgs {
  const __bf16* A[3];
  const __bf16* B[3];
  const float* bias[3];
  void* out[3];
  int mode[3];
};

__global__ __launch_bounds__(256) void gemm_bt(GemmArgs ga) {
  const int z = blockIdx.z;
  const __bf16* __restrict__ A  = ga.A[z];
  const __bf16* __restrict__ Bm = ga.B[z];
  const float* __restrict__ bias = ga.bias[z];
  void* Cout = ga.out[z];
  const int mode = ga.mode[z];

  __shared__ __align__(16) char sA[2][16384];
  __shared__ __align__(16) char sB[2][16384];
  const int tid = threadIdx.x;
  const int w = tid >> 6, l = tid & 63;
  const int wr = w >> 1, wc = w & 1;
  const int lg = l >> 4, lr = l & 15;
  const int m0 = blockIdx.y * 128, n0 = blockIdx.x * 128;

  f32x4 acc[4][4] = {};

  auto stage = [&](int k0, int buf) {
#pragma unroll
    for (int i = 0; i < 4; ++i) {
      int c = (i * 4 + w) * 64 + l;
      int row = c >> 3, ch = c & 7;
      gload_lds16(A + (size_t)(m0 + row) * 1024 + k0 + ((ch ^ (row & 7)) << 3),
                  &sA[buf][(i * 4 + w) * 1024]);
    }
#pragma unroll
    for (int i = 0; i < 4; ++i) {
      int c = (i * 4 + w) * 64 + l;
      int row = c >> 3, ch = c & 7;
      gload_lds16(Bm + (size_t)(n0 + row) * 1024 + k0 + ((ch ^ (row & 7)) << 3),
                  &sB[buf][(i * 4 + w) * 1024]);
    }
  };

  stage(0, 0);
  __syncthreads();

  for (int ks = 0; ks < 16; ++ks) {
    const int cur = ks & 1;
    if (ks < 15) stage((ks + 1) * 64, cur ^ 1);
#pragma unroll
    for (int kk = 0; kk < 2; ++kk) {
      bf16x8 af[4], bfv[4];
#pragma unroll
      for (int fm = 0; fm < 4; ++fm) {
        int row = wr * 64 + fm * 16 + lr;
        af[fm] = *(const bf16x8*)&sA[cur][row * 128 + (((kk * 4 + lg) ^ (row & 7)) << 4)];
      }
#pragma unroll
      for (int fn = 0; fn < 4; ++fn) {
        int row = wc * 64 + fn * 16 + lr;
        bfv[fn] = *(const bf16x8*)&sB[cur][row * 128 + (((kk * 4 + lg) ^ (row & 7)) << 4)];
      }
#pragma unroll
      for (int fm = 0; fm < 4; ++fm)
#pragma unroll
        for (int fn = 0; fn < 4; ++fn)
          acc[fm][fn] = mfma16(af[fm], bfv[fn], acc[fm][fn]);
    }
    __syncthreads();
  }

#pragma unroll
  for (int fm = 0; fm < 4; ++fm) {
#pragma unroll
    for (int fn = 0; fn < 4; ++fn) {
      const int n = n0 + wc * 64 + fn * 16 + lr;
      const int mb = m0 + wr * 64 + fm * 16 + 4 * lg;
      const float bval = bias[n];
      f32x4 vv = acc[fm][fn];
      if (mode == 2) {
        float* C = (float*)Cout;
#pragma unroll
        for (int r = 0; r < 4; ++r)
          C[(size_t)(mb + r) * 1024 + n] = vv[r] + bval;
      } else if (mode == 0) {
        __bf16* C = (__bf16*)Cout;
        const int hh = n >> 6, d = n & 63;
#pragma unroll
        for (int r = 0; r < 4; ++r) {
          int m = mb + r;
          C[(((size_t)(m >> 11) * 16 + hh) * 2048 + (m & 2047)) * 64 + d] =
              (__bf16)(vv[r] + bval);
        }
      } else {
        __bf16* C = (__bf16*)Cout;
        const int hh = n >> 6, d = n & 63;
        bf16x4 pk;
#pragma unroll
        for (int r = 0; r < 4; ++r) pk[r] = (__bf16)(vv[r] + bval);
        *(bf16x4*)(C + (((size_t)(mb >> 11) * 16 + hh) * 64 + d) * 2048 + (mb & 2047)) = pk;
      }
    }
  }
}

// ---------------- fused attention: producer/consumer wave split ----------------
// 512 thr = 8 waves. Waves 0-3 (PV): stage K/V, QK->softmax->bf16 P into LDS
// (double-buffered), PV MFMA, ctx. Waves 4-7 (store): read prev iter's P tile,
// cvt fp32, NT store -- their vmcnt FIFO holds ONLY stores -> counted vmcnt(6)
// gives 3 iters of drain slack without blocking staging or barriers.
// KVBLK=32, LDS 24.5KB -> 4 blocks/CU, grid 1024 = exactly one round.
__global__ __launch_bounds__(512) void attn_kernel(
    const __bf16* __restrict__ Qh, const __bf16* __restrict__ Kh,
    const __bf16* __restrict__ Vt, const uint32_t* __restrict__ mbits,
    float* __restrict__ attnW, __bf16* __restrict__ ctx)
{
  __shared__ __align__(16) char sK[2][4096];          // 32 k-rows x 128B
  __shared__ __align__(16) char sV[2][4096];          // 64 d-rows x 64B
  __shared__ __align__(16) char sPB[2][4][1024];      // bf16 P: 16 q x 32 k per qgrp
  __shared__ __align__(16) float sRed[2][4][16];

  const int tid = threadIdx.x;
  const int w = tid >> 6, l = tid & 63;
  const int lg = l >> 4, lr = l & 15;
  const int wq = w & 3;
  const bool isPV = (w < 4);
  const int msub = w >> 2;                 // pass-1 k-sub split across role groups

  const int bid = blockIdx.x;
  const int xcd = bid & 7, j = bid >> 3;
  const int bh = xcd * 4 + (j >> 5);       // head pinned to one XCD
  const int q0 = (j & 31) * 64;
  const int b = bh >> 4, h = bh & 15;

  const __bf16* qbase = Qh + ((size_t)bh * SS + q0 + wq * 16 + lr) * HD;
  bf16x8 qf0 = *(const bf16x8*)(qbase + lg * 8);
  bf16x8 qf1 = *(const bf16x8*)(qbase + 32 + lg * 8);

  const __bf16* Khead = Kh + (size_t)bh * SS * HD;
  const __bf16* Vhead = Vt + (size_t)bh * HD * SS;
  const uint32_t* mrow = mbits + b * 64;   // one 32-bit word per 32-k tile

  const int c0 = w * 64 + l;               // chunk id (PV waves: 0..255)

  auto stageK = [&](int k0, int buf) {
    int kr = c0 >> 3, ch = c0 & 7;
    gload_lds16(Khead + (size_t)(k0 + kr) * HD + ((ch ^ (kr & 7)) << 3),
                &sK[buf][w * 1024]);
  };
  auto stageV = [&](int k0, int buf) {
    int d = c0 >> 2, cs = c0 & 3;
    gload_lds16(Vhead + (size_t)d * SS + k0 + ((cs ^ (d & 3)) << 3),
                &sV[buf][w * 1024]);
  };

  // ================= pass 1: sumexp, k-rows split across all 8 waves ==========
  if (isPV) {
    stageK(0, 0);
    asm volatile("s_waitcnt vmcnt(0)" ::: "memory");
  }
  __builtin_amdgcn_s_barrier();

  float lsum = 0.0f;
  for (int t = 0; t < 64; ++t) {
    const int cur = t & 1;
    if (isPV && t < 63) stageK((t + 1) * 32, cur ^ 1);

    const uint32_t mw = mrow[t];
    const bool fast = (mw == 0xFFFFFFFFu);
    const int kr = msub * 16 + lr;
    bf16x8 k0f = *(const bf16x8*)&sK[cur][kr * 128 + ((lg ^ (kr & 7)) << 4)];
    bf16x8 k1f = *(const bf16x8*)&sK[cur][kr * 128 + (((4 + lg) ^ (kr & 7)) << 4)];
    f32x4 a = {};
    a = mfma16(k0f, qf0, a);
    a = mfma16(k1f, qf1, a);
    if (!fast) {
      uint32_t bits = mw >> (msub * 16 + 4 * lg);
#pragma unroll
      for (int r = 0; r < 4; ++r) a[r] = ((bits >> r) & 1) ? a[r] : NBRAW;
    }
#pragma unroll
    for (int r = 0; r < 4; ++r)
      lsum += __builtin_amdgcn_exp2f(fminf(a[r] * C2, 80.0f));

    if (isPV) asm volatile("s_waitcnt vmcnt(0)" ::: "memory");
    __builtin_amdgcn_s_barrier();
  }

  lsum += __shfl_xor(lsum, 16);
  lsum += __shfl_xor(lsum, 32);
  if (lg == 0) sRed[msub][wq][lr] = lsum;
  if (isPV) { stageK(0, 0); stageV(0, 0); }
  __syncthreads();                          // drains vmem + lds, publishes sRed

  const float rl = 1.0f / (sRed[0][wq][lr] + sRed[1][wq][lr]);

  f32x4 Oa[4] = {};
  float* pwbase = attnW + ((size_t)bh * SS + q0 + wq * 16) * SS;

  // ================= pass 2: PV waves produce, store waves drain ==============
  for (int t = 0; t < 64; ++t) {
    const int cur = t & 1;
    if (isPV) {
      if (t < 63) { stageK((t + 1) * 32, cur ^ 1); stageV((t + 1) * 32, cur ^ 1); }

      const uint32_t mw = mrow[t];
      const bool fast = (mw == 0xFFFFFFFFu);
      char* pbw = &sPB[cur][wq][0];
#pragma unroll
      for (int sub = 0; sub < 2; ++sub) {
        const int kr = sub * 16 + lr;
        bf16x8 k0f = *(const bf16x8*)&sK[cur][kr * 128 + ((lg ^ (kr & 7)) << 4)];
        bf16x8 k1f = *(const bf16x8*)&sK[cur][kr * 128 + (((4 + lg) ^ (kr & 7)) << 4)];
        __builtin_amdgcn_s_setprio(1);
        f32x4 a = {};
        a = mfma16(k0f, qf0, a);
        a = mfma16(k1f, qf1, a);
        __builtin_amdgcn_s_setprio(0);
        if (!fast) {
          uint32_t bits = mw >> (sub * 16 + 4 * lg);
#pragma unroll
          for (int r = 0; r < 4; ++r) a[r] = ((bits >> r) & 1) ? a[r] : NBRAW;
        }
        bf16x4 pk;
#pragma unroll
        for (int r = 0; r < 4; ++r)
          pk[r] = (__bf16)(__builtin_amdgcn_exp2f(fminf(a[r] * C2, 80.0f)) * rl);
        // row=lr, k-chunk c = sub*2+(lg>>1) (swz by row&3), half lg&1
        *(bf16x4*)&pbw[lr * 64 + (((sub * 2 + (lg >> 1)) ^ (lr & 3)) << 4) +
                       ((lg & 1) << 3)] = pk;
      }
      // PV: A = P row lr (8 k elems, chunk lg), B = V^T rows
      bf16x8 pa = *(const bf16x8*)&pbw[lr * 64 + ((lg ^ (lr & 3)) << 4)];
      __builtin_amdgcn_s_setprio(1);
#pragma unroll
      for (int dg = 0; dg < 4; ++dg) {
        const int d = dg * 16 + lr;
        bf16x8 vb = *(const bf16x8*)&sV[cur][d * 64 + ((lg ^ (d & 3)) << 4)];
        Oa[dg] = mfma16(pa, vb, Oa[dg]);
      }
      __builtin_amdgcn_s_setprio(0);
      asm volatile("s_waitcnt vmcnt(0) lgkmcnt(0)" ::: "memory");
    } else {
      if (t > 0) {
        const int pb = (t - 1) & 1;
        const char* pbr = &sPB[pb][wq][0];
        const int row = l >> 2, cc = l & 3;
        bf16x8 pv8 = *(const bf16x8*)&pbr[row * 64 + ((cc ^ (row & 3)) << 4)];
        f32x4 lo, hi;
#pragma unroll
        for (int r = 0; r < 4; ++r) { lo[r] = (float)pv8[r]; hi[r] = (float)pv8[4 + r]; }
        float* dst = pwbase + (size_t)row * SS + (t - 1) * 32 + cc * 8;
        __builtin_nontemporal_store(lo, (f32x4*)dst);
        __builtin_nontemporal_store(hi, (f32x4*)(dst + 4));
      }
      // FIFO = stores only: keep <=6 in flight (3 iters slack), never full drain
      asm volatile("s_waitcnt vmcnt(6) lgkmcnt(0)" ::: "memory");
    }
    __builtin_amdgcn_s_barrier();
  }

  if (isPV) {
    // ctx -> [b*s][h*64+d] bf16 (Oa: q = 4lg+r, d = dg*16+lr)
#pragma unroll
    for (int dg = 0; dg < 4; ++dg)
#pragma unroll
      for (int r = 0; r < 4; ++r)
        ctx[(size_t)(b * SS + q0 + wq * 16 + 4 * lg + r) * DIMM + h * HD + dg * 16 + lr] =
            (__bf16)Oa[dg][r];
  } else {
    // drain final tile 63 (sPB[1] still valid; last loop barrier published it)
    const char* pbr = &sPB[1][wq][0];
    const int row = l >> 2, cc = l & 3;
    bf16x8 pv8 = *(const bf16x8*)&pbr[row * 64 + ((cc ^ (row & 3)) << 4)];
    f32x4 lo, hi;
#pragma unroll
    for (int r = 0; r < 4; ++r) { lo[r] = (float)pv8[r]; hi[r] = (float)pv8[4 + r]; }
    float* dst = pwbase + (size_t)row * SS + 63 * 32 + cc * 8;
    __builtin_nontemporal_store(lo, (f32x4*)dst);
    __builtin_nontemporal_store(hi, (f32x4*)(dst + 4));
  }
}

// ---------------- launch ----------------
extern "C" void kernel_launch(void* const* d_in, const int* in_sizes, int n_in,
                              void* d_out, int out_size, void* d_ws, size_t ws_size,
                              hipStream_t stream)
{
  const float* q   = (const float*)d_in[0];
  const float* k   = (const float*)d_in[1];
  const float* v   = (const float*)d_in[2];
  const int*   msk = (const int*)d_in[3];
  const float* Wq  = (const float*)d_in[4];
  const float* bq  = (const float*)d_in[5];
  const float* Wk  = (const float*)d_in[6];
  const float* bk  = (const float*)d_in[7];
  const float* Wv  = (const float*)d_in[8];
  const float* bv  = (const float*)d_in[9];
  const float* Wo  = (const float*)d_in[10];
  const float* bo  = (const float*)d_in[11];

  char* ws = (char*)d_ws;
  __bf16* xq  = (__bf16*)(ws);
  __bf16* xk  = (__bf16*)(ws + (8u << 20));
  __bf16* xv  = (__bf16*)(ws + (16u << 20));
  __bf16* wqb = (__bf16*)(ws + (24u << 20));
  __bf16* wkb = (__bf16*)(ws + (26u << 20));
  __bf16* wvb = (__bf16*)(ws + (28u << 20));
  __bf16* wob = (__bf16*)(ws + (30u << 20));
  __bf16* Qh  = (__bf16*)(ws + (32u << 20));
  __bf16* Kh  = (__bf16*)(ws + (40u << 20));
  __bf16* Vt  = (__bf16*)(ws + (48u << 20));
  __bf16* ctx = (__bf16*)(ws + (56u << 20));
  uint32_t* mbits = (uint32_t*)(ws + (64u << 20));

  CvtArgs ca;
  ca.src[0] = q;  ca.dst[0] = xq;  ca.n[0] = NTOK * DIMM;
  ca.src[1] = k;  ca.dst[1] = xk;  ca.n[1] = NTOK * DIMM;
  ca.src[2] = v;  ca.dst[2] = xv;  ca.n[2] = NTOK * DIMM;
  ca.src[3] = Wq; ca.dst[3] = wqb; ca.n[3] = DIMM * DIMM;
  ca.src[4] = Wk; ca.dst[4] = wkb; ca.n[4] = DIMM * DIMM;
  ca.src[5] = Wv; ca.dst[5] = wvb; ca.n[5] = DIMM * DIMM;
  ca.src[6] = Wo; ca.dst[6] = wob; ca.n[6] = DIMM * DIMM;
  cvt_kernel<<<dim3(2048, 7, 1), 256, 0, stream>>>(ca);
  maskbits_kernel<<<1, 128, 0, stream>>>(msk, mbits);

  GemmArgs g1;
  g1.A[0] = xq; g1.B[0] = wqb; g1.bias[0] = bq; g1.out[0] = (void*)Qh; g1.mode[0] = 0;
  g1.A[1] = xk; g1.B[1] = wkb; g1.bias[1] = bk; g1.out[1] = (void*)Kh; g1.mode[1] = 0;
  g1.A[2] = xv; g1.B[2] = wvb; g1.bias[2] = bv; g1.out[2] = (void*)Vt; g1.mode[2] = 1;
  gemm_bt<<<dim3(8, 32, 3), 256, 0, stream>>>(g1);

  float* out = (float*)d_out;
  float* attnW = out + (size_t)NTOK * DIMM;
  attn_kernel<<<dim3(1024, 1, 1), 512, 0, stream>>>(Qh, Kh, Vt, mbits, attnW, ctx);

  GemmArgs g2;
  g2.A[0] = ctx; g2.B[0] = wob; g2.bias[0] = bo; g2.out[0] = (void*)out; g2.mode[0] = 2;
  g2.A[1] = ctx; g2.B[1] = wob; g2.bias[1] = bo; g2.out[1] = (void*)out; g2.mode[1] = 2;
  g2.A[2] = ctx; g2.B[2] = wob; g2.bias[2] = bo; g2.out[2] = (void*)out; g2.mode[2] = 2;
  gemm_bt<<<dim3(8, 32, 1), 256, 0, stream>>>(g2);
}

// Round 14
// 258.649 us; speedup vs baseline: 1.7408x; 1.4247x over previous
//
#include <hip/hip_runtime.h>
#include <hip/hip_bf16.h>
#include <stdint.h>

#define DIMM 1024
#define HEADS 16
#define HD 64
#define BB 2
#define SS 2048
#define NTOK (BB*SS)

typedef __attribute__((ext_vector_type(8))) __bf16 bf16x8;
typedef __attribute__((ext_vector_type(4))) __bf16 bf16x4;
typedef __attribute__((ext_vector_type(4))) float f32x4;

__device__ __forceinline__ f32x4 mfma16(bf16x8 a, bf16x8 b, f32x4 c) {
  return __builtin_amdgcn_mfma_f32_16x16x32_bf16(a, b, c, 0, 0, 0);
}

__device__ __forceinline__ void gload_lds16(const void* g, void* l) {
  __builtin_amdgcn_global_load_lds(
      (__attribute__((address_space(1))) void*)(void*)g,
      (__attribute__((address_space(3))) void*)l,
      16, 0, 0);
}

#define LOG2E 1.4426950408889634f
#define C2 (0.125f * LOG2E)      /* score scale folded into log2 domain */
#define NBRAW (-8e9f)            /* raw-domain masked score: -8e9*0.125 = -1e9 */

// ---------------- convert fp32 -> bf16 ----------------
struct CvtArgs {
  const float* src[7];
  __bf16* dst[7];
  int n[7];
};

__global__ __launch_bounds__(256) void cvt_kernel(CvtArgs a) {
  const int t = blockIdx.y;
  const long i = ((long)blockIdx.x * 256 + threadIdx.x) * 8;
  if (i >= a.n[t]) return;
  const float* s = a.src[t] + i;
  f32x4 x0 = *(const f32x4*)s;
  f32x4 x1 = *(const f32x4*)(s + 4);
  bf16x8 o;
  o[0] = (__bf16)x0[0]; o[1] = (__bf16)x0[1]; o[2] = (__bf16)x0[2]; o[3] = (__bf16)x0[3];
  o[4] = (__bf16)x1[0]; o[5] = (__bf16)x1[1]; o[6] = (__bf16)x1[2]; o[7] = (__bf16)x1[3];
  *(bf16x8*)(a.dst[t] + i) = o;
}

// ---------------- mask -> bitmask (128 words: [b][k>>5]) ----------------
__global__ void maskbits_kernel(const int* __restrict__ msk, uint32_t* __restrict__ mbits) {
  int j = threadIdx.x;
  if (j >= 128) return;
  const int* src = msk + j * 32;
  uint32_t wdd = 0;
#pragma unroll
  for (int i = 0; i < 32; ++i) wdd |= (src[i] != 0 ? 1u : 0u) << i;
  mbits[j] = wdd;
}

// ---------------- GEMM: C[m,n] = sum_k A[m,k]*B[n,k] + bias[n] ----------------
struct GemmArgs {
  const __bf16* A[3];
  const __bf16* B[3];
  const float* bias[3];
  void* out[3];
  int mode[3];
};

__global__ __launch_bounds__(256) void gemm_bt(GemmArgs ga) {
  const int z = blockIdx.z;
  const __bf16* __restrict__ A  = ga.A[z];
  const __bf16* __restrict__ Bm = ga.B[z];
  const float* __restrict__ bias = ga.bias[z];
  void* Cout = ga.out[z];
  const int mode = ga.mode[z];

  __shared__ __align__(16) char sA[2][16384];
  __shared__ __align__(16) char sB[2][16384];
  const int tid = threadIdx.x;
  const int w = tid >> 6, l = tid & 63;
  const int wr = w >> 1, wc = w & 1;
  const int lg = l >> 4, lr = l & 15;
  const int m0 = blockIdx.y * 128, n0 = blockIdx.x * 128;

  f32x4 acc[4][4] = {};

  auto stage = [&](int k0, int buf) {
#pragma unroll
    for (int i = 0; i < 4; ++i) {
      int c = (i * 4 + w) * 64 + l;
      int row = c >> 3, ch = c & 7;
      gload_lds16(A + (size_t)(m0 + row) * 1024 + k0 + ((ch ^ (row & 7)) << 3),
                  &sA[buf][(i * 4 + w) * 1024]);
    }
#pragma unroll
    for (int i = 0; i < 4; ++i) {
      int c = (i * 4 + w) * 64 + l;
      int row = c >> 3, ch = c & 7;
      gload_lds16(Bm + (size_t)(n0 + row) * 1024 + k0 + ((ch ^ (row & 7)) << 3),
                  &sB[buf][(i * 4 + w) * 1024]);
    }
  };

  stage(0, 0);
  __syncthreads();

  for (int ks = 0; ks < 16; ++ks) {
    const int cur = ks & 1;
    if (ks < 15) stage((ks + 1) * 64, cur ^ 1);
#pragma unroll
    for (int kk = 0; kk < 2; ++kk) {
      bf16x8 af[4], bfv[4];
#pragma unroll
      for (int fm = 0; fm < 4; ++fm) {
        int row = wr * 64 + fm * 16 + lr;
        af[fm] = *(const bf16x8*)&sA[cur][row * 128 + (((kk * 4 + lg) ^ (row & 7)) << 4)];
      }
#pragma unroll
      for (int fn = 0; fn < 4; ++fn) {
        int row = wc * 64 + fn * 16 + lr;
        bfv[fn] = *(const bf16x8*)&sB[cur][row * 128 + (((kk * 4 + lg) ^ (row & 7)) << 4)];
      }
#pragma unroll
      for (int fm = 0; fm < 4; ++fm)
#pragma unroll
        for (int fn = 0; fn < 4; ++fn)
          acc[fm][fn] = mfma16(af[fm], bfv[fn], acc[fm][fn]);
    }
    __syncthreads();
  }

#pragma unroll
  for (int fm = 0; fm < 4; ++fm) {
#pragma unroll
    for (int fn = 0; fn < 4; ++fn) {
      const int n = n0 + wc * 64 + fn * 16 + lr;
      const int mb = m0 + wr * 64 + fm * 16 + 4 * lg;
      const float bval = bias[n];
      f32x4 vv = acc[fm][fn];
      if (mode == 2) {
        float* C = (float*)Cout;
#pragma unroll
        for (int r = 0; r < 4; ++r)
          C[(size_t)(mb + r) * 1024 + n] = vv[r] + bval;
      } else if (mode == 0) {
        __bf16* C = (__bf16*)Cout;
        const int hh = n >> 6, d = n & 63;
#pragma unroll
        for (int r = 0; r < 4; ++r) {
          int m = mb + r;
          C[(((size_t)(m >> 11) * 16 + hh) * 2048 + (m & 2047)) * 64 + d] =
              (__bf16)(vv[r] + bval);
        }
      } else {
        __bf16* C = (__bf16*)Cout;
        const int hh = n >> 6, d = n & 63;
        bf16x4 pk;
#pragma unroll
        for (int r = 0; r < 4; ++r) pk[r] = (__bf16)(vv[r] + bval);
        *(bf16x4*)(C + (((size_t)(mb >> 11) * 16 + hh) * 64 + d) * 2048 + (mb & 2047)) = pk;
      }
    }
  }
}

// ---------------- fused attention ----------------
// R9 structure with KVBLK=32 + TRIPLE-buffered K/V staging: barrier(t) waits
// on loads issued at iter t-1, which sit AHEAD of stores(t-1) in the vmcnt
// FIFO -> stores get 2 iterations of drain slack and never block the barrier.
// LDS = 3x4K(sK) + 3x4K(sV) + 8K(sPF) = 32KB -> 5 blocks/CU. grid 1024.
__global__ __launch_bounds__(256) void attn_kernel(
    const __bf16* __restrict__ Qh, const __bf16* __restrict__ Kh,
    const __bf16* __restrict__ Vt, const uint32_t* __restrict__ mbits,
    float* __restrict__ attnW, __bf16* __restrict__ ctx)
{
  __shared__ __align__(16) char sK[3][4096];        // 32 k-rows x 128B
  __shared__ __align__(16) char sV[3][4096];        // 64 d-rows x 64B
  __shared__ __align__(16) float sPF[4][16][32];    // wave-private P tile (f32)

  const int tid = threadIdx.x;
  const int w = tid >> 6, l = tid & 63;
  const int lg = l >> 4, lr = l & 15;

  const int bid = blockIdx.x;
  const int xcd = bid & 7, j = bid >> 3;
  const int bh = xcd * 4 + (j >> 5);      // each head pinned to one XCD
  const int q0 = (j & 31) * 64;
  const int b = bh >> 4, h = bh & 15;

  const __bf16* qbase = Qh + ((size_t)bh * SS + q0 + w * 16 + lr) * HD;
  bf16x8 qf0 = *(const bf16x8*)(qbase + lg * 8);
  bf16x8 qf1 = *(const bf16x8*)(qbase + 32 + lg * 8);

  const __bf16* Khead = Kh + (size_t)bh * SS * HD;
  const __bf16* Vhead = Vt + (size_t)bh * HD * SS;
  const uint32_t* mrow = mbits + b * 64;  // one word per 32-k tile

  const int c0 = w * 64 + l;              // chunk id 0..255

  auto stageK = [&](int k0, int buf) {    // one gload per wave
    int kr = c0 >> 3, ch = c0 & 7;
    gload_lds16(Khead + (size_t)(k0 + kr) * HD + ((ch ^ (kr & 7)) << 3),
                &sK[buf][w * 1024]);
  };
  auto stageV = [&](int k0, int buf) {
    int d = c0 >> 2, cs = c0 & 3;
    gload_lds16(Vhead + (size_t)d * SS + k0 + ((cs ^ (d & 3)) << 3),
                &sV[buf][w * 1024]);
  };

  // ---- pass 1: per-row sumexp (max-free, clamped). lane q = lr, k = 4lg+r ----
  stageK(0, 0);
  stageK(32, 1);
  asm volatile("s_waitcnt vmcnt(1)" ::: "memory");  // buf0 ready
  __builtin_amdgcn_s_barrier();

  float lsum = 0.0f;

  for (int t = 0; t < 64; ++t) {
    const int cur = t % 3;
    if (t < 62) stageK((t + 2) * 32, (t + 2) % 3);

    const uint32_t mw = mrow[t];
    const bool fast = (mw == 0xFFFFFFFFu);

#pragma unroll
    for (int sub = 0; sub < 2; ++sub) {
      const int kr = sub * 16 + lr;
      bf16x8 k0f = *(const bf16x8*)&sK[cur][kr * 128 + ((lg ^ (kr & 7)) << 4)];
      bf16x8 k1f = *(const bf16x8*)&sK[cur][kr * 128 + (((4 + lg) ^ (kr & 7)) << 4)];
      __builtin_amdgcn_s_setprio(1);
      f32x4 a = {};
      a = mfma16(k0f, qf0, a);
      a = mfma16(k1f, qf1, a);
      __builtin_amdgcn_s_setprio(0);
      if (!fast) {
        uint32_t bits = mw >> (sub * 16 + 4 * lg);
#pragma unroll
        for (int r = 0; r < 4; ++r) a[r] = ((bits >> r) & 1) ? a[r] : NBRAW;
      }
#pragma unroll
      for (int r = 0; r < 4; ++r)
        lsum += __builtin_amdgcn_exp2f(fminf(a[r] * C2, 80.0f));
    }
    // retire loads(t+1) (issued last iter); keep loads(t+2) in flight
    asm volatile("s_waitcnt vmcnt(1)" ::: "memory");
    __builtin_amdgcn_s_barrier();
  }

  lsum += __shfl_xor(lsum, 16);
  lsum += __shfl_xor(lsum, 32);
  const float rl = 1.0f / lsum;

  f32x4 Oa[4] = {};
  float* pwbase = attnW + ((size_t)bh * SS + q0 + w * 16) * SS;

  // ---- pass 2: QK -> sPF -> 128B-line NT store -> PV; 2-iter store slack ----
  stageK(0, 0); stageV(0, 0);
  stageK(32, 1); stageV(32, 1);
  asm volatile("s_waitcnt vmcnt(2)" ::: "memory");  // buf0 ready
  __builtin_amdgcn_s_barrier();

  for (int t = 0; t < 64; ++t) {
    const int cur = t % 3;
    if (t < 62) { stageK((t + 2) * 32, (t + 2) % 3); stageV((t + 2) * 32, (t + 2) % 3); }

    const uint32_t mw = mrow[t];
    const bool fast = (mw == 0xFFFFFFFFu);

    // -- compute 2 sub-tiles (32 k-cols), write f32 P into sPF (swizzled) --
#pragma unroll
    for (int sub = 0; sub < 2; ++sub) {
      const int kr = sub * 16 + lr;
      bf16x8 k0f = *(const bf16x8*)&sK[cur][kr * 128 + ((lg ^ (kr & 7)) << 4)];
      bf16x8 k1f = *(const bf16x8*)&sK[cur][kr * 128 + (((4 + lg) ^ (kr & 7)) << 4)];
      __builtin_amdgcn_s_setprio(1);
      f32x4 a = {};
      a = mfma16(k0f, qf0, a);
      a = mfma16(k1f, qf1, a);
      __builtin_amdgcn_s_setprio(0);
      if (!fast) {
        uint32_t bits = mw >> (sub * 16 + 4 * lg);
#pragma unroll
        for (int r = 0; r < 4; ++r) a[r] = ((bits >> r) & 1) ? a[r] : NBRAW;
      }
      f32x4 p;
#pragma unroll
      for (int r = 0; r < 4; ++r)
        p[r] = __builtin_amdgcn_exp2f(fminf(a[r] * C2, 80.0f)) * rl;
      const int cp = (sub * 4 + lg) ^ (lr & 7);     // 16B chunk, swizzled
      *(f32x4*)&sPF[w][lr][cp * 4] = p;
    }

    // -- transposed NT store: 2 instrs x (8 rows x 128B contiguous lines) --
#pragma unroll
    for (int s2 = 0; s2 < 2; ++s2) {
      const int row = s2 * 8 + (l >> 3);
      const int cp = (l & 7) ^ (row & 7);
      f32x4 pv4 = *(const f32x4*)&sPF[w][row][cp * 4];
      __builtin_nontemporal_store(pv4,
          (f32x4*)(pwbase + (size_t)row * SS + t * 32 + 4 * (l & 7)));
    }

    // -- PV: A-operand from sPF (f32 -> bf16), B = V^T rows --
    f32x4 pa_lo = *(const f32x4*)&sPF[w][lr][(((2 * lg) ^ (lr & 7)) * 4)];
    f32x4 pa_hi = *(const f32x4*)&sPF[w][lr][(((2 * lg + 1) ^ (lr & 7)) * 4)];
    bf16x8 pa;
#pragma unroll
    for (int r = 0; r < 4; ++r) {
      pa[r] = (__bf16)pa_lo[r];
      pa[4 + r] = (__bf16)pa_hi[r];
    }
    __builtin_amdgcn_s_setprio(1);
#pragma unroll
    for (int dg = 0; dg < 4; ++dg) {
      const int d = dg * 16 + lr;
      bf16x8 vb = *(const bf16x8*)&sV[cur][d * 64 + ((lg ^ (d & 3)) << 4)];
      Oa[dg] = mfma16(pa, vb, Oa[dg]);
    }
    __builtin_amdgcn_s_setprio(0);

    // retire loads(t+1) only (issued iter t-1, AHEAD of stores(t-1) in FIFO);
    // all stores + loads(t+2) stay in flight -> stores get 2 iters of slack.
    asm volatile("s_waitcnt vmcnt(6)" ::: "memory");
    __builtin_amdgcn_s_barrier();
  }

  // epilogue: context -> [b*s][h*64+d] bf16 (Oa: q = 4lg+r, d = dg*16+lr)
#pragma unroll
  for (int dg = 0; dg < 4; ++dg)
#pragma unroll
    for (int r = 0; r < 4; ++r)
      ctx[(size_t)(b * SS + q0 + w * 16 + 4 * lg + r) * DIMM + h * HD + dg * 16 + lr] =
          (__bf16)Oa[dg][r];
}

// ---------------- launch ----------------
extern "C" void kernel_launch(void* const* d_in, const int* in_sizes, int n_in,
                              void* d_out, int out_size, void* d_ws, size_t ws_size,
                              hipStream_t stream)
{
  const float* q   = (const float*)d_in[0];
  const float* k   = (const float*)d_in[1];
  const float* v   = (const float*)d_in[2];
  const int*   msk = (const int*)d_in[3];
  const float* Wq  = (const float*)d_in[4];
  const float* bq  = (const float*)d_in[5];
  const float* Wk  = (const float*)d_in[6];
  const float* bk  = (const float*)d_in[7];
  const float* Wv  = (const float*)d_in[8];
  const float* bv  = (const float*)d_in[9];
  const float* Wo  = (const float*)d_in[10];
  const float* bo  = (const float*)d_in[11];

  char* ws = (char*)d_ws;
  __bf16* xq  = (__bf16*)(ws);
  __bf16* xk  = (__bf16*)(ws + (8u << 20));
  __bf16* xv  = (__bf16*)(ws + (16u << 20));
  __bf16* wqb = (__bf16*)(ws + (24u << 20));
  __bf16* wkb = (__bf16*)(ws + (26u << 20));
  __bf16* wvb = (__bf16*)(ws + (28u << 20));
  __bf16* wob = (__bf16*)(ws + (30u << 20));
  __bf16* Qh  = (__bf16*)(ws + (32u << 20));
  __bf16* Kh  = (__bf16*)(ws + (40u << 20));
  __bf16* Vt  = (__bf16*)(ws + (48u << 20));
  __bf16* ctx = (__bf16*)(ws + (56u << 20));
  uint32_t* mbits = (uint32_t*)(ws + (64u << 20));

  CvtArgs ca;
  ca.src[0] = q;  ca.dst[0] = xq;  ca.n[0] = NTOK * DIMM;
  ca.src[1] = k;  ca.dst[1] = xk;  ca.n[1] = NTOK * DIMM;
  ca.src[2] = v;  ca.dst[2] = xv;  ca.n[2] = NTOK * DIMM;
  ca.src[3] = Wq; ca.dst[3] = wqb; ca.n[3] = DIMM * DIMM;
  ca.src[4] = Wk; ca.dst[4] = wkb; ca.n[4] = DIMM * DIMM;
  ca.src[5] = Wv; ca.dst[5] = wvb; ca.n[5] = DIMM * DIMM;
  ca.src[6] = Wo; ca.dst[6] = wob; ca.n[6] = DIMM * DIMM;
  cvt_kernel<<<dim3(2048, 7, 1), 256, 0, stream>>>(ca);
  maskbits_kernel<<<1, 128, 0, stream>>>(msk, mbits);

  GemmArgs g1;
  g1.A[0] = xq; g1.B[0] = wqb; g1.bias[0] = bq; g1.out[0] = (void*)Qh; g1.mode[0] = 0;
  g1.A[1] = xk; g1.B[1] = wkb; g1.bias[1] = bk; g1.out[1] = (void*)Kh; g1.mode[1] = 0;
  g1.A[2] = xv; g1.B[2] = wvb; g1.bias[2] = bv; g1.out[2] = (void*)Vt; g1.mode[2] = 1;
  gemm_bt<<<dim3(8, 32, 3), 256, 0, stream>>>(g1);

  float* out = (float*)d_out;
  float* attnW = out + (size_t)NTOK * DIMM;
  attn_kernel<<<dim3(1024, 1, 1), 256, 0, stream>>>(Qh, Kh, Vt, mbits, attnW, ctx);

  GemmArgs g2;
  g2.A[0] = ctx; g2.B[0] = wob; g2.bias[0] = bo; g2.out[0] = (void*)out; g2.mode[0] = 2;
  g2.A[1] = ctx; g2.B[1] = wob; g2.bias[1] = bo; g2.out[1] = (void*)out; g2.mode[1] = 2;
  g2.A[2] = ctx; g2.B[2] = wob; g2.bias[2] = bo; g2.out[2] = (void*)out; g2.mode[2] = 2;
  gemm_bt<<<dim3(8, 32, 1), 256, 0, stream>>>(g2);
}

// Round 15
// 244.053 us; speedup vs baseline: 1.8449x; 1.0598x over previous
//
#include <hip/hip_runtime.h>
#include <hip/hip_bf16.h>
#include <stdint.h>

#define DIMM 1024
#define HEADS 16
#define HD 64
#define BB 2
#define SS 2048
#define NTOK (BB*SS)

typedef __attribute__((ext_vector_type(8))) __bf16 bf16x8;
typedef __attribute__((ext_vector_type(4))) __bf16 bf16x4;
typedef __attribute__((ext_vector_type(4))) float f32x4;

__device__ __forceinline__ f32x4 mfma16(bf16x8 a, bf16x8 b, f32x4 c) {
  return __builtin_amdgcn_mfma_f32_16x16x32_bf16(a, b, c, 0, 0, 0);
}

__device__ __forceinline__ void gload_lds16(const void* g, void* l) {
  __builtin_amdgcn_global_load_lds(
      (__attribute__((address_space(1))) void*)(void*)g,
      (__attribute__((address_space(3))) void*)l,
      16, 0, 0);
}

#define LOG2E 1.4426950408889634f
#define C2 (0.125f * LOG2E)      /* score scale folded into log2 domain */
#define NBRAW (-8e9f)            /* raw-domain masked score: -8e9*0.125 = -1e9 */

// ---------------- convert fp32 -> bf16 ----------------
struct CvtArgs {
  const float* src[7];
  __bf16* dst[7];
  int n[7];
};

__global__ __launch_bounds__(256) void cvt_kernel(CvtArgs a) {
  const int t = blockIdx.y;
  const long i = ((long)blockIdx.x * 256 + threadIdx.x) * 8;
  if (i >= a.n[t]) return;
  const float* s = a.src[t] + i;
  f32x4 x0 = *(const f32x4*)s;
  f32x4 x1 = *(const f32x4*)(s + 4);
  bf16x8 o;
  o[0] = (__bf16)x0[0]; o[1] = (__bf16)x0[1]; o[2] = (__bf16)x0[2]; o[3] = (__bf16)x0[3];
  o[4] = (__bf16)x1[0]; o[5] = (__bf16)x1[1]; o[6] = (__bf16)x1[2]; o[7] = (__bf16)x1[3];
  *(bf16x8*)(a.dst[t] + i) = o;
}

// ---------------- mask -> bitmask (128 words: [b][k>>5]) ----------------
__global__ void maskbits_kernel(const int* __restrict__ msk, uint32_t* __restrict__ mbits) {
  int j = threadIdx.x;
  if (j >= 128) return;
  const int* src = msk + j * 32;
  uint32_t wdd = 0;
#pragma unroll
  for (int i = 0; i < 32; ++i) wdd |= (src[i] != 0 ? 1u : 0u) << i;
  mbits[j] = wdd;
}

// ---------------- GEMM: C[m,n] = sum_k A[m,k]*B[n,k] + bias[n] ----------------
struct GemmArgs {
  const __bf16* A[3];
  const __bf16* B[3];
  const float* bias[3];
  void* out[3];
  int mode[3];
};

__global__ __launch_bounds__(256) void gemm_bt(GemmArgs ga) {
  const int z = blockIdx.z;
  const __bf16* __restrict__ A  = ga.A[z];
  const __bf16* __restrict__ Bm = ga.B[z];
  const float* __restrict__ bias = ga.bias[z];
  void* Cout = ga.out[z];
  const int mode = ga.mode[z];

  __shared__ __align__(16) char sA[2][16384];
  __shared__ __align__(16) char sB[2][16384];
  const int tid = threadIdx.x;
  const int w = tid >> 6, l = tid & 63;
  const int wr = w >> 1, wc = w & 1;
  const int lg = l >> 4, lr = l & 15;
  const int m0 = blockIdx.y * 128, n0 = blockIdx.x * 128;

  f32x4 acc[4][4] = {};

  auto stage = [&](int k0, int buf) {
#pragma unroll
    for (int i = 0; i < 4; ++i) {
      int c = (i * 4 + w) * 64 + l;
      int row = c >> 3, ch = c & 7;
      gload_lds16(A + (size_t)(m0 + row) * 1024 + k0 + ((ch ^ (row & 7)) << 3),
                  &sA[buf][(i * 4 + w) * 1024]);
    }
#pragma unroll
    for (int i = 0; i < 4; ++i) {
      int c = (i * 4 + w) * 64 + l;
      int row = c >> 3, ch = c & 7;
      gload_lds16(Bm + (size_t)(n0 + row) * 1024 + k0 + ((ch ^ (row & 7)) << 3),
                  &sB[buf][(i * 4 + w) * 1024]);
    }
  };

  stage(0, 0);
  __syncthreads();

  for (int ks = 0; ks < 16; ++ks) {
    const int cur = ks & 1;
    if (ks < 15) stage((ks + 1) * 64, cur ^ 1);
#pragma unroll
    for (int kk = 0; kk < 2; ++kk) {
      bf16x8 af[4], bfv[4];
#pragma unroll
      for (int fm = 0; fm < 4; ++fm) {
        int row = wr * 64 + fm * 16 + lr;
        af[fm] = *(const bf16x8*)&sA[cur][row * 128 + (((kk * 4 + lg) ^ (row & 7)) << 4)];
      }
#pragma unroll
      for (int fn = 0; fn < 4; ++fn) {
        int row = wc * 64 + fn * 16 + lr;
        bfv[fn] = *(const bf16x8*)&sB[cur][row * 128 + (((kk * 4 + lg) ^ (row & 7)) << 4)];
      }
#pragma unroll
      for (int fm = 0; fm < 4; ++fm)
#pragma unroll
        for (int fn = 0; fn < 4; ++fn)
          acc[fm][fn] = mfma16(af[fm], bfv[fn], acc[fm][fn]);
    }
    __syncthreads();
  }

#pragma unroll
  for (int fm = 0; fm < 4; ++fm) {
#pragma unroll
    for (int fn = 0; fn < 4; ++fn) {
      const int n = n0 + wc * 64 + fn * 16 + lr;
      const int mb = m0 + wr * 64 + fm * 16 + 4 * lg;
      const float bval = bias[n];
      f32x4 vv = acc[fm][fn];
      if (mode == 2) {
        float* C = (float*)Cout;
#pragma unroll
        for (int r = 0; r < 4; ++r)
          C[(size_t)(mb + r) * 1024 + n] = vv[r] + bval;
      } else if (mode == 0) {
        __bf16* C = (__bf16*)Cout;
        const int hh = n >> 6, d = n & 63;
#pragma unroll
        for (int r = 0; r < 4; ++r) {
          int m = mb + r;
          C[(((size_t)(m >> 11) * 16 + hh) * 2048 + (m & 2047)) * 64 + d] =
              (__bf16)(vv[r] + bval);
        }
      } else {
        __bf16* C = (__bf16*)Cout;
        const int hh = n >> 6, d = n & 63;
        bf16x4 pk;
#pragma unroll
        for (int r = 0; r < 4; ++r) pk[r] = (__bf16)(vv[r] + bval);
        *(bf16x4*)(C + (((size_t)(mb >> 11) * 16 + hh) * 64 + d) * 2048 + (mb & 2047)) = pk;
      }
    }
  }
}

// ---------------- fused attention ----------------
// R9 structure (best: 248us) with ONE change: P buffered as bf16 over the
// FULL 64-col iter (sPB[4][16][64] bf16 = 8KB, same LDS total 40KB ->
// 4 blocks/CU), so the NT store phase emits 4 instrs x 4 rows x 256B
// contiguous runs (vs R9's 2 x 8 x 128B). Tests run-length 128->256B
// without the R11 occupancy confound.
__global__ __launch_bounds__(256) void attn_kernel(
    const __bf16* __restrict__ Qh, const __bf16* __restrict__ Kh,
    const __bf16* __restrict__ Vt, const uint32_t* __restrict__ mbits,
    float* __restrict__ attnW, __bf16* __restrict__ ctx)
{
  __shared__ __align__(16) char sK[2][8192];
  __shared__ __align__(16) char sV[2][8192];
  __shared__ __align__(16) __bf16 sPB[4][16][64];   // wave-private P, bf16

  const int tid = threadIdx.x;
  const int w = tid >> 6, l = tid & 63;
  const int lg = l >> 4, lr = l & 15;

  const int bid = blockIdx.x;
  const int xcd = bid & 7, j = bid >> 3;
  const int bh = xcd * 4 + (j >> 5);      // each head pinned to one XCD
  const int q0 = (j & 31) * 64;
  const int b = bh >> 4, h = bh & 15;

  const __bf16* qbase = Qh + ((size_t)bh * SS + q0 + w * 16 + lr) * HD;
  bf16x8 qf0 = *(const bf16x8*)(qbase + lg * 8);
  bf16x8 qf1 = *(const bf16x8*)(qbase + 32 + lg * 8);

  const __bf16* Khead = Kh + (size_t)bh * SS * HD;
  const __bf16* Vhead = Vt + (size_t)bh * HD * SS;
  const uint32_t* mrow = mbits + b * 64;

  const int c0 = w * 64 + l;

  auto stageK = [&](int k0, int buf) {
#pragma unroll
    for (int i = 0; i < 2; ++i) {
      int c = i * 256 + c0;
      int kr = c >> 3, ch = c & 7;
      gload_lds16(Khead + (size_t)(k0 + kr) * HD + ((ch ^ (kr & 7)) << 3),
                  &sK[buf][(i * 4 + w) * 1024]);
    }
  };
  auto stageV = [&](int k0, int buf) {
#pragma unroll
    for (int i = 0; i < 2; ++i) {
      int c = i * 256 + c0;
      int d = c >> 3, ch = c & 7;
      gload_lds16(Vhead + (size_t)d * SS + k0 + ((ch ^ (d & 7)) << 3),
                  &sV[buf][(i * 4 + w) * 1024]);
    }
  };

  // ---- pass 1: per-row sumexp (max-free, clamped). lane q = lr, k = 4lg+r ----
  stageK(0, 0);
  asm volatile("s_waitcnt vmcnt(0)" ::: "memory");
  __builtin_amdgcn_s_barrier();

  float lsum = 0.0f;

  for (int t = 0; t < 32; ++t) {
    const int cur = t & 1;
    if (t < 31) stageK((t + 1) * 64, cur ^ 1);

    const uint32_t mw0 = mrow[2 * t], mw1 = mrow[2 * t + 1];
    const bool fast = ((mw0 & mw1) == 0xFFFFFFFFu);

#pragma unroll
    for (int sub = 0; sub < 4; ++sub) {
      const int kr = sub * 16 + lr;
      bf16x8 k0f = *(const bf16x8*)&sK[cur][kr * 128 + ((lg ^ (kr & 7)) << 4)];
      bf16x8 k1f = *(const bf16x8*)&sK[cur][kr * 128 + (((4 + lg) ^ (kr & 7)) << 4)];
      __builtin_amdgcn_s_setprio(1);
      f32x4 a = {};
      a = mfma16(k0f, qf0, a);
      a = mfma16(k1f, qf1, a);
      __builtin_amdgcn_s_setprio(0);
      if (!fast) {
        uint32_t bits = ((sub < 2) ? mw0 : mw1) >> ((sub & 1) * 16 + 4 * lg);
#pragma unroll
        for (int r = 0; r < 4; ++r) a[r] = ((bits >> r) & 1) ? a[r] : NBRAW;
      }
#pragma unroll
      for (int r = 0; r < 4; ++r)
        lsum += __builtin_amdgcn_exp2f(fminf(a[r] * C2, 80.0f));
    }
    asm volatile("s_waitcnt vmcnt(0)" ::: "memory");
    __builtin_amdgcn_s_barrier();
  }

  lsum += __shfl_xor(lsum, 16);
  lsum += __shfl_xor(lsum, 32);
  const float rl = 1.0f / lsum;

  f32x4 Oa[4] = {};
  float* pwbase = attnW + ((size_t)bh * SS + q0 + w * 16) * SS;

  // ---- pass 2: P(bf16) via LDS-transpose + 256B-run NT store + PV ----
  stageK(0, 0);
  stageV(0, 0);
  asm volatile("s_waitcnt vmcnt(0)" ::: "memory");
  __builtin_amdgcn_s_barrier();

  for (int t = 0; t < 32; ++t) {
    const int cur = t & 1;
    if (t < 31) { stageK((t + 1) * 64, cur ^ 1); stageV((t + 1) * 64, cur ^ 1); }

    const uint32_t mw0 = mrow[2 * t], mw1 = mrow[2 * t + 1];
    const bool fast = ((mw0 & mw1) == 0xFFFFFFFFu);

    // -- compute 4 sub-tiles (64 k-cols); lane holds P[q=lr][k=sub*16+4lg+r] --
    // write bf16x4 to sPB row lr, 16B chunk c = sub*2+(lg>>1) swizzled ^(lr&7)
#pragma unroll
    for (int sub = 0; sub < 4; ++sub) {
      const int kr = sub * 16 + lr;
      bf16x8 k0f = *(const bf16x8*)&sK[cur][kr * 128 + ((lg ^ (kr & 7)) << 4)];
      bf16x8 k1f = *(const bf16x8*)&sK[cur][kr * 128 + (((4 + lg) ^ (kr & 7)) << 4)];
      __builtin_amdgcn_s_setprio(1);
      f32x4 a = {};
      a = mfma16(k0f, qf0, a);
      a = mfma16(k1f, qf1, a);
      __builtin_amdgcn_s_setprio(0);
      if (!fast) {
        uint32_t bits = ((sub < 2) ? mw0 : mw1) >> ((sub & 1) * 16 + 4 * lg);
#pragma unroll
        for (int r = 0; r < 4; ++r) a[r] = ((bits >> r) & 1) ? a[r] : NBRAW;
      }
      bf16x4 pk;
#pragma unroll
      for (int r = 0; r < 4; ++r)
        pk[r] = (__bf16)(__builtin_amdgcn_exp2f(fminf(a[r] * C2, 80.0f)) * rl);
      const int cc = ((sub * 2 + (lg >> 1)) ^ (lr & 7));
      *(bf16x4*)((char*)&sPB[w][lr][0] + cc * 16 + (lg & 1) * 8) = pk;
    }

    // -- transposed NT store: 4 instrs x (4 rows x 256B contiguous runs) --
#pragma unroll
    for (int i = 0; i < 4; ++i) {
      const int row = i * 4 + (l >> 4);
      const int jj = l & 15;                 // 4 fp32 cols per lane
      const int cc = (jj >> 1) ^ (row & 7);
      bf16x4 pb = *(const bf16x4*)((const char*)&sPB[w][row][0] + cc * 16 + (jj & 1) * 8);
      f32x4 pv;
#pragma unroll
      for (int r = 0; r < 4; ++r) pv[r] = (float)pb[r];
      __builtin_nontemporal_store(pv,
          (f32x4*)(pwbase + (size_t)row * SS + t * 64 + jj * 4));
    }

    // -- PV: A-operand bf16x8 direct from sPB (chunk hh*4+lg ^ (lr&7)) --
#pragma unroll
    for (int hh = 0; hh < 2; ++hh) {
      bf16x8 pa = *(const bf16x8*)((const char*)&sPB[w][lr][0] +
                                   (((hh * 4 + lg) ^ (lr & 7)) * 16));
      __builtin_amdgcn_s_setprio(1);
#pragma unroll
      for (int dg = 0; dg < 4; ++dg) {
        const int d = dg * 16 + lr;
        bf16x8 vb = *(const bf16x8*)&sV[cur][d * 128 + (((hh * 4 + lg) ^ (d & 7)) << 4)];
        Oa[dg] = mfma16(pa, vb, Oa[dg]);
      }
      __builtin_amdgcn_s_setprio(0);
    }

    // counted drain: retire the 4 staging loads, leave the 4 NT stores in flight
    asm volatile("s_waitcnt vmcnt(4)" ::: "memory");
    __builtin_amdgcn_s_barrier();
  }

  // epilogue: context -> [b*s][h*64+d] bf16 (Oa: q = 4lg+r, d = dg*16+lr)
#pragma unroll
  for (int dg = 0; dg < 4; ++dg)
#pragma unroll
    for (int r = 0; r < 4; ++r)
      ctx[(size_t)(b * SS + q0 + w * 16 + 4 * lg + r) * DIMM + h * HD + dg * 16 + lr] =
          (__bf16)Oa[dg][r];
}

// ---------------- launch ----------------
extern "C" void kernel_launch(void* const* d_in, const int* in_sizes, int n_in,
                              void* d_out, int out_size, void* d_ws, size_t ws_size,
                              hipStream_t stream)
{
  const float* q   = (const float*)d_in[0];
  const float* k   = (const float*)d_in[1];
  const float* v   = (const float*)d_in[2];
  const int*   msk = (const int*)d_in[3];
  const float* Wq  = (const float*)d_in[4];
  const float* bq  = (const float*)d_in[5];
  const float* Wk  = (const float*)d_in[6];
  const float* bk  = (const float*)d_in[7];
  const float* Wv  = (const float*)d_in[8];
  const float* bv  = (const float*)d_in[9];
  const float* Wo  = (const float*)d_in[10];
  const float* bo  = (const float*)d_in[11];

  char* ws = (char*)d_ws;
  __bf16* xq  = (__bf16*)(ws);
  __bf16* xk  = (__bf16*)(ws + (8u << 20));
  __bf16* xv  = (__bf16*)(ws + (16u << 20));
  __bf16* wqb = (__bf16*)(ws + (24u << 20));
  __bf16* wkb = (__bf16*)(ws + (26u << 20));
  __bf16* wvb = (__bf16*)(ws + (28u << 20));
  __bf16* wob = (__bf16*)(ws + (30u << 20));
  __bf16* Qh  = (__bf16*)(ws + (32u << 20));
  __bf16* Kh  = (__bf16*)(ws + (40u << 20));
  __bf16* Vt  = (__bf16*)(ws + (48u << 20));
  __bf16* ctx = (__bf16*)(ws + (56u << 20));
  uint32_t* mbits = (uint32_t*)(ws + (64u << 20));

  CvtArgs ca;
  ca.src[0] = q;  ca.dst[0] = xq;  ca.n[0] = NTOK * DIMM;
  ca.src[1] = k;  ca.dst[1] = xk;  ca.n[1] = NTOK * DIMM;
  ca.src[2] = v;  ca.dst[2] = xv;  ca.n[2] = NTOK * DIMM;
  ca.src[3] = Wq; ca.dst[3] = wqb; ca.n[3] = DIMM * DIMM;
  ca.src[4] = Wk; ca.dst[4] = wkb; ca.n[4] = DIMM * DIMM;
  ca.src[5] = Wv; ca.dst[5] = wvb; ca.n[5] = DIMM * DIMM;
  ca.src[6] = Wo; ca.dst[6] = wob; ca.n[6] = DIMM * DIMM;
  cvt_kernel<<<dim3(2048, 7, 1), 256, 0, stream>>>(ca);
  maskbits_kernel<<<1, 128, 0, stream>>>(msk, mbits);

  GemmArgs g1;
  g1.A[0] = xq; g1.B[0] = wqb; g1.bias[0] = bq; g1.out[0] = (void*)Qh; g1.mode[0] = 0;
  g1.A[1] = xk; g1.B[1] = wkb; g1.bias[1] = bk; g1.out[1] = (void*)Kh; g1.mode[1] = 0;
  g1.A[2] = xv; g1.B[2] = wvb; g1.bias[2] = bv; g1.out[2] = (void*)Vt; g1.mode[2] = 1;
  gemm_bt<<<dim3(8, 32, 3), 256, 0, stream>>>(g1);

  float* out = (float*)d_out;
  float* attnW = out + (size_t)NTOK * DIMM;
  attn_kernel<<<dim3(1024, 1, 1), 256, 0, stream>>>(Qh, Kh, Vt, mbits, attnW, ctx);

  GemmArgs g2;
  g2.A[0] = ctx; g2.B[0] = wob; g2.bias[0] = bo; g2.out[0] = (void*)out; g2.mode[0] = 2;
  g2.A[1] = ctx; g2.B[1] = wob; g2.bias[1] = bo; g2.out[1] = (void*)out; g2.mode[1] = 2;
  g2.A[2] = ctx; g2.B[2] = wob; g2.bias[2] = bo; g2.out[2] = (void*)out; g2.mode[2] = 2;
  gemm_bt<<<dim3(8, 32, 1), 256, 0, stream>>>(g2);
}